// Round 7
// baseline (335.438 us; speedup 1.0000x reference)
//
#include <hip/hip_runtime.h>
#include <math.h>

#define BATCH 2
#define SLEN 2048
#define DM 1024
#define NH 16
#define DK 64
#define STILES (SLEN / 64)  // 32

typedef __attribute__((ext_vector_type(8))) __bf16 bf16x8;
typedef __attribute__((ext_vector_type(4))) float f32x4;

__device__ __forceinline__ unsigned short f2bf(float x) {  // round-nearest
  unsigned u = __builtin_bit_cast(unsigned, x);
  unsigned r = (u + 0x7fffu + ((u >> 16) & 1u)) >> 16;
  return (unsigned short)r;
}
// cheap truncation split: x ~= hi + lo to ~2^-16 relative
__device__ __forceinline__ void splitbf(float x, unsigned short& h,
                                        unsigned short& l) {
  unsigned u = __builtin_bit_cast(unsigned, x);
  h = (unsigned short)(u >> 16);
  float hf = __builtin_bit_cast(float, u & 0xffff0000u);
  l = (unsigned short)(__builtin_bit_cast(unsigned, x - hf) >> 16);
}

// async global->LDS, 16 B per lane
__device__ __forceinline__ void gld16(const unsigned short* g,
                                      unsigned short* l) {
  __builtin_amdgcn_global_load_lds(
      (const __attribute__((address_space(1))) void*)g,
      (__attribute__((address_space(3))) void*)l, 16, 0, 0);
}

// ---------------------------------------------------------------------------
// Weight transpose+split -> Wt[n][packed k], 64-u16 k-blocks [hi32|lo32],
// 16-B chunks XOR-swizzled with key (n&7).
// ---------------------------------------------------------------------------
__global__ __launch_bounds__(256)
void convert_w(const float* __restrict__ Wq, const float* __restrict__ Wk,
               const float* __restrict__ Wv, unsigned short* __restrict__ Wqt,
               unsigned short* __restrict__ Wkt,
               unsigned short* __restrict__ Wvt) {
  const int kb = blockIdx.x, h = blockIdx.y, z = blockIdx.z;
  const float* W = (z == 0 ? Wq : z == 1 ? Wk : Wv) +
                   ((size_t)h * DM + kb * 64) * DK;
  unsigned short* D = (z == 0 ? Wqt : z == 1 ? Wkt : Wvt);

  __shared__ float T[64][65];
  const int tid = threadIdx.x;
  {
    int r = tid >> 2, c0 = (tid & 3) * 16;
#pragma unroll
    for (int i = 0; i < 4; ++i) {
      float4 f = *(const float4*)(W + (size_t)r * DK + c0 + i * 4);
      T[r][c0 + i * 4 + 0] = f.x;
      T[r][c0 + i * 4 + 1] = f.y;
      T[r][c0 + i * 4 + 2] = f.z;
      T[r][c0 + i * 4 + 3] = f.w;
    }
  }
  __syncthreads();
  int j = tid >> 2, p = tid & 3;
  int n = h * 64 + j;
  int kloc = p * 16;
  unsigned short hi[16], lo[16];
#pragma unroll
  for (int i = 0; i < 16; ++i) splitbf(T[kloc + i][j], hi[i], lo[i]);
  int kglob = kb * 64 + kloc;
  int blk = kglob >> 5;
  int c0 = (kglob & 31) >> 3;
  int key = n & 7;
  unsigned short* rowp = D + (size_t)n * 2048 + blk * 64;
  uint4 u0, u1;
  u0.x = (unsigned)hi[0] | ((unsigned)hi[1] << 16);
  u0.y = (unsigned)hi[2] | ((unsigned)hi[3] << 16);
  u0.z = (unsigned)hi[4] | ((unsigned)hi[5] << 16);
  u0.w = (unsigned)hi[6] | ((unsigned)hi[7] << 16);
  u1.x = (unsigned)hi[8] | ((unsigned)hi[9] << 16);
  u1.y = (unsigned)hi[10] | ((unsigned)hi[11] << 16);
  u1.z = (unsigned)hi[12] | ((unsigned)hi[13] << 16);
  u1.w = (unsigned)hi[14] | ((unsigned)hi[15] << 16);
  *(uint4*)(rowp + ((c0 ^ key)) * 8) = u0;
  *(uint4*)(rowp + (((c0 + 1) ^ key)) * 8) = u1;
  u0.x = (unsigned)lo[0] | ((unsigned)lo[1] << 16);
  u0.y = (unsigned)lo[2] | ((unsigned)lo[3] << 16);
  u0.z = (unsigned)lo[4] | ((unsigned)lo[5] << 16);
  u0.w = (unsigned)lo[6] | ((unsigned)lo[7] << 16);
  u1.x = (unsigned)lo[8] | ((unsigned)lo[9] << 16);
  u1.y = (unsigned)lo[10] | ((unsigned)lo[11] << 16);
  u1.z = (unsigned)lo[12] | ((unsigned)lo[13] << 16);
  u1.w = (unsigned)lo[14] | ((unsigned)lo[15] << 16);
  *(uint4*)(rowp + (((c0 + 4) ^ key)) * 8) = u0;
  *(uint4*)(rowp + (((c0 + 5) ^ key)) * 8) = u1;
}

// ---------------------------------------------------------------------------
// X pre-split: X[m][k] fp32 -> Xp[z][m][packed k] (swizzle key m&7).
// grid (4096, 3), block 256.
// ---------------------------------------------------------------------------
__global__ __launch_bounds__(256)
void convert_x(const float* __restrict__ Q, const float* __restrict__ K,
               const float* __restrict__ V, unsigned short* __restrict__ Xp) {
  const int m = blockIdx.x, z = blockIdx.y;
  const float* src = (z == 0 ? Q : z == 1 ? K : V) + (size_t)m * DM;
  unsigned short* dst =
      Xp + (size_t)z * (8u * 1024 * 1024) + (size_t)m * 2048;
  const int k0 = threadIdx.x * 4;
  float4 f = *(const float4*)(src + k0);
  ushort4 h4, l4;
  splitbf(f.x, h4.x, l4.x);
  splitbf(f.y, h4.y, l4.y);
  splitbf(f.z, h4.z, l4.z);
  splitbf(f.w, h4.w, l4.w);
  int blk = k0 >> 5, ch = (k0 & 31) >> 3, off = k0 & 7, key = m & 7;
  unsigned short* rowp = dst + blk * 64;
  *(ushort4*)(rowp + ((ch ^ key)) * 8 + off) = h4;
  *(ushort4*)(rowp + (((ch + 4) ^ key)) * 8 + off) = l4;
}

// ---------------------------------------------------------------------------
// Wo pre-split: Wo[n][k] fp32 -> Wot[n][packed k] (swizzled like Wt).
// Runs AFTER attn (q_all region dead). grid 1024, block 256.
// ---------------------------------------------------------------------------
__global__ __launch_bounds__(256)
void convert_wo(const float* __restrict__ Wo, unsigned short* __restrict__ Wot) {
  const int n = blockIdx.x;
  const int t = threadIdx.x;
  const int k0 = t * 4;
  float4 f = *(const float4*)(Wo + (size_t)n * DM + k0);
  ushort4 h4, l4;
  splitbf(f.x, h4.x, l4.x);
  splitbf(f.y, h4.y, l4.y);
  splitbf(f.z, h4.z, l4.z);
  splitbf(f.w, h4.w, l4.w);
  int blk = k0 >> 5, ch = (k0 & 31) >> 3, off = k0 & 7, key = n & 7;
  unsigned short* rowp = Wot + (size_t)n * 2048 + blk * 64;
  *(ushort4*)(rowp + ((ch ^ key)) * 8 + off) = h4;
  *(ushort4*)(rowp + (((ch + 4) ^ key)) * 8 + off) = l4;
}

// ---------------------------------------------------------------------------
// 256x256 proj GEMM, race-free 1-phase-per-K-step counted-vmcnt schedule.
// Phase t: stage(t+1 -> buf[(t+1)&1]) at top -- that buffer's K-step t-1
// readers were ALL sealed by the previous end-barrier, so no cross-wave
// DMA-land-vs-ds_read race (the R1-R5 schedules staged into a half being
// read in the same inter-barrier region -- fixed here). VMW(8) keeps the
// fresh stage in flight (counted, never drain-0); reads buf[t&1] only.
// B frags read ONCE per K-step (8 reads, vs 2x in the QM-split schedules);
// A read as QM0 (8) with lgkm(8) so QM1's 8 reads land under the QM0 MFMA
// cluster. 96 MFMA / 24 ds_reads / 2 barriers / 1 vmcnt per K-step.
// ---------------------------------------------------------------------------
__global__ __launch_bounds__(512, 2)
void proj_gemm(const unsigned short* __restrict__ Xp,
               const unsigned short* __restrict__ Wqt,
               const unsigned short* __restrict__ Wkt,
               const unsigned short* __restrict__ Wvt,
               const float* __restrict__ bq, const float* __restrict__ bk,
               const float* __restrict__ bv, unsigned short* __restrict__ q_all,
               unsigned short* __restrict__ k_all,
               unsigned short* __restrict__ vt) {
  const int ntile = blockIdx.x, mt = blockIdx.y, z = blockIdx.z;
  const unsigned short* Bw = (z == 0 ? Wqt : z == 1 ? Wkt : Wvt);
  const float* bias = (z == 0 ? bq : z == 1 ? bk : bv);

  __shared__ alignas(16) unsigned short As[2][256 * 64];
  __shared__ alignas(16) unsigned short Bs[2][256 * 64];

  const int tid = threadIdx.x;
  const int lane = tid & 63, w = tid >> 6;
  const int l15 = lane & 15, quad = lane >> 4;
  const int wm = (w >> 2) * 128, wn = (w & 3) * 64;
  const int kx = l15 & 7;

  const unsigned short* Ap =
      Xp + (size_t)z * (8u * 1024 * 1024) + (size_t)(mt * 256) * 2048;
  const unsigned short* Bp = Bw + (size_t)(ntile * 256) * 2048;

  // full-tile linear stage: 4 A chunks + 4 B chunks per thread (8 gld16)
#define STAGE(bf, t)                                                          \
  do {                                                                        \
    _Pragma("unroll") for (int it_ = 0; it_ < 4; ++it_) {                     \
      int s_ = tid + it_ * 512;                                               \
      int r_ = s_ >> 3, sg_ = s_ & 7;                                         \
      gld16(Ap + (size_t)r_ * 2048 + (t)*64 + sg_ * 8, &As[bf][s_ * 8]);      \
    }                                                                         \
    _Pragma("unroll") for (int it_ = 0; it_ < 4; ++it_) {                     \
      int s_ = tid + it_ * 512;                                               \
      int r_ = s_ >> 3, sg_ = s_ & 7;                                         \
      gld16(Bp + (size_t)r_ * 2048 + (t)*64 + sg_ * 8, &Bs[bf][s_ * 8]);      \
    }                                                                         \
  } while (0)
#define VMW(n) asm volatile("s_waitcnt vmcnt(" #n ")" ::: "memory")

  f32x4 acc[2][2][4][2];
#pragma unroll
  for (int a0 = 0; a0 < 2; ++a0)
#pragma unroll
    for (int a1 = 0; a1 < 2; ++a1)
#pragma unroll
      for (int a2 = 0; a2 < 4; ++a2)
#pragma unroll
        for (int a3 = 0; a3 < 2; ++a3)
          acc[a0][a1][a2][a3] = (f32x4){0.f, 0.f, 0.f, 0.f};

  STAGE(0, 0);

#pragma unroll 1
  for (int t = 0; t < 32; ++t) {
    const int buf = t & 1;
    if (t + 1 < 32) {
      STAGE(buf ^ 1, t + 1);  // target sealed by previous end-barrier
      VMW(8);                 // own stage(t) landed; stage(t+1) in flight
    } else {
      VMW(0);
    }
    __builtin_amdgcn_s_barrier();  // all waves' stage(t) landed

    // B frags once per K-step (8 reads) + A-QM0 (8 reads)
    bf16x8 bh[2][2], bl[2][2];
#pragma unroll
    for (int qn = 0; qn < 2; ++qn)
#pragma unroll
      for (int j = 0; j < 2; ++j) {
        const unsigned short* p = &Bs[buf][(wn + qn * 32 + j * 16 + l15) * 64];
        bh[qn][j] = *(const bf16x8*)(p + ((quad ^ kx)) * 8);
        bl[qn][j] = *(const bf16x8*)(p + (((quad + 4) ^ kx)) * 8);
      }
    bf16x8 ah[4], al[4];
#pragma unroll
    for (int i = 0; i < 4; ++i) {
      const unsigned short* p = &As[buf][(wm + i * 16 + l15) * 64];
      ah[i] = *(const bf16x8*)(p + ((quad ^ kx)) * 8);
      al[i] = *(const bf16x8*)(p + (((quad + 4) ^ kx)) * 8);
    }
    // A-QM1 (8 reads) issued now; lgkm(8) below lets them land under QM0 MFMA
    bf16x8 ah1[4], al1[4];
#pragma unroll
    for (int i = 0; i < 4; ++i) {
      const unsigned short* p = &As[buf][(wm + 64 + i * 16 + l15) * 64];
      ah1[i] = *(const bf16x8*)(p + ((quad ^ kx)) * 8);
      al1[i] = *(const bf16x8*)(p + (((quad + 4) ^ kx)) * 8);
    }
    asm volatile("s_waitcnt lgkmcnt(8)" ::: "memory");  // B+A0 done
    __builtin_amdgcn_sched_barrier(0);
    __builtin_amdgcn_s_setprio(1);
#pragma unroll
    for (int qn = 0; qn < 2; ++qn)
#pragma unroll
      for (int j = 0; j < 2; ++j)
#pragma unroll
        for (int i = 0; i < 4; ++i) {
          acc[0][qn][i][j] = __builtin_amdgcn_mfma_f32_16x16x32_bf16(
              ah[i], bh[qn][j], acc[0][qn][i][j], 0, 0, 0);
          acc[0][qn][i][j] = __builtin_amdgcn_mfma_f32_16x16x32_bf16(
              al[i], bh[qn][j], acc[0][qn][i][j], 0, 0, 0);
          acc[0][qn][i][j] = __builtin_amdgcn_mfma_f32_16x16x32_bf16(
              ah[i], bl[qn][j], acc[0][qn][i][j], 0, 0, 0);
        }
    __builtin_amdgcn_s_setprio(0);
    asm volatile("s_waitcnt lgkmcnt(0)" ::: "memory");  // A1 done
    __builtin_amdgcn_sched_barrier(0);
    __builtin_amdgcn_s_setprio(1);
#pragma unroll
    for (int qn = 0; qn < 2; ++qn)
#pragma unroll
      for (int j = 0; j < 2; ++j)
#pragma unroll
        for (int i = 0; i < 4; ++i) {
          acc[1][qn][i][j] = __builtin_amdgcn_mfma_f32_16x16x32_bf16(
              ah1[i], bh[qn][j], acc[1][qn][i][j], 0, 0, 0);
          acc[1][qn][i][j] = __builtin_amdgcn_mfma_f32_16x16x32_bf16(
              al1[i], bh[qn][j], acc[1][qn][i][j], 0, 0, 0);
          acc[1][qn][i][j] = __builtin_amdgcn_mfma_f32_16x16x32_bf16(
              ah1[i], bl[qn][j], acc[1][qn][i][j], 0, 0, 0);
        }
    __builtin_amdgcn_s_setprio(0);
    __builtin_amdgcn_sched_barrier(0);
    __builtin_amdgcn_s_barrier();  // seal this phase's reads
  }
#undef VMW
#undef STAGE

  if (z <= 1) {
    unsigned short* dst = (z == 0 ? q_all : k_all);
#pragma unroll
    for (int qm = 0; qm < 2; ++qm)
#pragma unroll
      for (int qn = 0; qn < 2; ++qn)
#pragma unroll
        for (int i = 0; i < 4; ++i)
#pragma unroll
          for (int j = 0; j < 2; ++j) {
            int n = ntile * 256 + wn + qn * 32 + j * 16 + l15;
            int hh_ = n >> 6, d = n & 63;
            int chi = (d >> 5) * 8 + ((d & 31) >> 3);
            float bn = bias[n];
#pragma unroll
            for (int r = 0; r < 4; ++r) {
              int m = mt * 256 + wm + qm * 64 + i * 16 + quad * 4 + r;
              int key = m & 15;
              size_t rb = (size_t)m * 2048 + hh_ * 128;
              unsigned short hv, lv;
              splitbf(acc[qm][qn][i][j][r] + bn, hv, lv);
              dst[rb + ((chi ^ key)) * 8 + (d & 7)] = hv;
              dst[rb + (((chi + 4) ^ key)) * 8 + (d & 7)] = lv;
            }
          }
  } else {
#pragma unroll
    for (int qm = 0; qm < 2; ++qm)
#pragma unroll
      for (int qn = 0; qn < 2; ++qn)
#pragma unroll
        for (int i = 0; i < 4; ++i)
#pragma unroll
          for (int j = 0; j < 2; ++j) {
            int n = ntile * 256 + wn + qn * 32 + j * 16 + l15;
            int h = n >> 6, d = n & 63;
            float bn = bias[n];
            int m0 = mt * 256 + wm + qm * 64 + i * 16 + quad * 4;
            int b = m0 >> 11, s0_ = m0 & 2047;
            int kt = s0_ >> 6, sl = s0_ & 63;
            int ch = sl >> 3, off = sl & 7, key = d & 15;
            ushort4 h4, l4;
            splitbf(acc[qm][qn][i][j][0] + bn, h4.x, l4.x);
            splitbf(acc[qm][qn][i][j][1] + bn, h4.y, l4.y);
            splitbf(acc[qm][qn][i][j][2] + bn, h4.z, l4.z);
            splitbf(acc[qm][qn][i][j][3] + bn, h4.w, l4.w);
            size_t base =
                (size_t)(b * NH + h) * 262144 + (size_t)d * 4096 + kt * 128;
            *(ushort4*)(vt + base + ((ch ^ key)) * 8 + off) = h4;
            *(ushort4*)(vt + base + (((ch + 8) ^ key)) * 8 + off) = l4;
          }
  }
}

// ---------------------------------------------------------------------------
// Output GEMM, same race-free counted-vmcnt template at 256x64 tile.
// grid (16 ntile, 16 mt) = 256 blocks = 1/CU, 512 threads (8 waves as 4Mx2N,
// 64x32 out each), LDS 80 KB (A 2x32K, B 2x16K... A 2x32K + B 2x8K).
// 5 loads/thread/K-step (4 A + 1 B) -> VMW(5); 12 ds_reads, 24 MFMA,
// 2 barriers per K-step.
// ---------------------------------------------------------------------------
__global__ __launch_bounds__(512, 2)
void out_gemm(const unsigned short* __restrict__ a_all,
              const unsigned short* __restrict__ Wot,
              const float* __restrict__ bo, float* __restrict__ out) {
  const int ntile = blockIdx.x, mt = blockIdx.y;

  __shared__ alignas(16) unsigned short As[2][256 * 64];  // 64 KB
  __shared__ alignas(16) unsigned short Bs[2][64 * 64];   // 16 KB

  const int tid = threadIdx.x;
  const int lane = tid & 63, w = tid >> 6;
  const int l15 = lane & 15, quad = lane >> 4;
  const int wm = (w >> 1) * 64, wn = (w & 1) * 32;
  const int kx = l15 & 7;

  const unsigned short* Ap = a_all + (size_t)(mt * 256) * 2048;
  const unsigned short* Bp = Wot + (size_t)(ntile * 64) * 2048;

#define STAGEO(bf, t)                                                         \
  do {                                                                        \
    _Pragma("unroll") for (int it_ = 0; it_ < 4; ++it_) {                     \
      int s_ = tid + it_ * 512;                                               \
      int r_ = s_ >> 3, sg_ = s_ & 7;                                         \
      gld16(Ap + (size_t)r_ * 2048 + (t)*64 + sg_ * 8, &As[bf][s_ * 8]);      \
    }                                                                         \
    {                                                                         \
      int s_ = tid;                                                           \
      int r_ = s_ >> 3, sg_ = s_ & 7;                                         \
      gld16(Bp + (size_t)r_ * 2048 + (t)*64 + sg_ * 8, &Bs[bf][s_ * 8]);      \
    }                                                                         \
  } while (0)
#define VMW(n) asm volatile("s_waitcnt vmcnt(" #n ")" ::: "memory")

  f32x4 acc[4][2];
#pragma unroll
  for (int i = 0; i < 4; ++i)
#pragma unroll
    for (int j = 0; j < 2; ++j) acc[i][j] = (f32x4){0.f, 0.f, 0.f, 0.f};

  STAGEO(0, 0);

#pragma unroll 1
  for (int t = 0; t < 32; ++t) {
    const int buf = t & 1;
    if (t + 1 < 32) {
      STAGEO(buf ^ 1, t + 1);
      VMW(5);
    } else {
      VMW(0);
    }
    __builtin_amdgcn_s_barrier();

    bf16x8 bh[2], bl[2];
#pragma unroll
    for (int j = 0; j < 2; ++j) {
      const unsigned short* p = &Bs[buf][(wn + j * 16 + l15) * 64];
      bh[j] = *(const bf16x8*)(p + ((quad ^ kx)) * 8);
      bl[j] = *(const bf16x8*)(p + (((quad + 4) ^ kx)) * 8);
    }
    bf16x8 ah[4], al[4];
#pragma unroll
    for (int i = 0; i < 4; ++i) {
      const unsigned short* p = &As[buf][(wm + i * 16 + l15) * 64];
      ah[i] = *(const bf16x8*)(p + ((quad ^ kx)) * 8);
      al[i] = *(const bf16x8*)(p + (((quad + 4) ^ kx)) * 8);
    }
    asm volatile("s_waitcnt lgkmcnt(0)" ::: "memory");
    __builtin_amdgcn_sched_barrier(0);
    __builtin_amdgcn_s_setprio(1);
#pragma unroll
    for (int j = 0; j < 2; ++j)
#pragma unroll
      for (int i = 0; i < 4; ++i) {
        acc[i][j] = __builtin_amdgcn_mfma_f32_16x16x32_bf16(ah[i], bh[j], acc[i][j], 0, 0, 0);
        acc[i][j] = __builtin_amdgcn_mfma_f32_16x16x32_bf16(al[i], bh[j], acc[i][j], 0, 0, 0);
        acc[i][j] = __builtin_amdgcn_mfma_f32_16x16x32_bf16(ah[i], bl[j], acc[i][j], 0, 0, 0);
      }
    __builtin_amdgcn_s_setprio(0);
    __builtin_amdgcn_sched_barrier(0);
    __builtin_amdgcn_s_barrier();
  }
#undef VMW
#undef STAGEO

#pragma unroll
  for (int i = 0; i < 4; ++i)
#pragma unroll
    for (int j = 0; j < 2; ++j) {
      int n = ntile * 64 + wn + j * 16 + l15;
      float bn = bo[n];
#pragma unroll
      for (int r = 0; r < 4; ++r) {
        int m = mt * 256 + wm + i * 16 + quad * 4 + r;
        out[(size_t)m * DM + n] = acc[i][j][r] + bn;
      }
    }
}

// ---------------------------------------------------------------------------
// MFMA flash attention with swapped QK^T + packed P-writes (unchanged from
// the passing R4/R5 version).
// ---------------------------------------------------------------------------
__global__ __launch_bounds__(256)
void attn_kernel(const unsigned short* __restrict__ q_all,
                 const unsigned short* __restrict__ k_all,
                 const unsigned short* __restrict__ vt,
                 unsigned short* __restrict__ a_all) {
  const int qt = blockIdx.x, h = blockIdx.y, b = blockIdx.z;
  const unsigned short* vp = vt + (size_t)(b * NH + h) * 262144;

  __shared__ alignas(16) unsigned short Ks[2][64 * 128];
  __shared__ alignas(16) unsigned short Vs[2][64 * 128];
  __shared__ alignas(16) unsigned short Ps[128 * 64];

  const int tid = threadIdx.x;
  const int lane = tid & 63;
  const int w = tid >> 6;
  const int l15 = lane & 15;
  const int quad = lane >> 4;

  bf16x8 qf[2][2][2];
#pragma unroll
  for (int rt = 0; rt < 2; ++rt) {
    const unsigned short* qrow =
        q_all + (size_t)(b * SLEN + qt * 128 + w * 32 + rt * 16 + l15) * 2048 +
        h * 128;
#pragma unroll
    for (int kb = 0; kb < 2; ++kb) {
      qf[rt][kb][0] = *(const bf16x8*)(qrow + ((kb * 8 + quad) ^ l15) * 8);
      qf[rt][kb][1] = *(const bf16x8*)(qrow + ((kb * 8 + quad + 4) ^ l15) * 8);
    }
  }

  // prologue: stage kt=0
  {
    const unsigned short* ksrc = k_all + (size_t)(b * SLEN) * 2048 + h * 128;
#pragma unroll
    for (int it = 0; it < 4; ++it) {
      int ss = it * 256 + tid;
      int r = ss >> 4, p = ss & 15;
      gld16(ksrc + (size_t)r * 2048 + p * 8, &Ks[0][ss * 8]);
    }
#pragma unroll
    for (int it = 0; it < 4; ++it) {
      int ss = it * 256 + tid;
      int d = ss >> 4, p = ss & 15;
      gld16(vp + (size_t)d * 4096 + p * 8, &Vs[0][ss * 8]);
    }
  }

  f32x4 o[2][4];
  float lpart[2];
#pragma unroll
  for (int rt = 0; rt < 2; ++rt) {
    lpart[rt] = 0.f;
#pragma unroll
    for (int nt = 0; nt < 4; ++nt) o[rt][nt] = (f32x4){0.f, 0.f, 0.f, 0.f};
  }

  int cur = 0;
  for (int kt = 0; kt < STILES; ++kt) {
    __syncthreads();  // glds(kt) done (aged through prev iteration for kt>0)

    if (kt + 1 < STILES) {  // prefetch kt+1 into alt buffers
      const unsigned short* ksrc =
          k_all + (size_t)(b * SLEN + (kt + 1) * 64) * 2048 + h * 128;
#pragma unroll
      for (int it = 0; it < 4; ++it) {
        int ss = it * 256 + tid;
        int r = ss >> 4, p = ss & 15;
        gld16(ksrc + (size_t)r * 2048 + p * 8, &Ks[cur ^ 1][ss * 8]);
      }
#pragma unroll
      for (int it = 0; it < 4; ++it) {
        int ss = it * 256 + tid;
        int d = ss >> 4, p = ss & 15;
        gld16(vp + (size_t)d * 4096 + (kt + 1) * 128 + p * 8,
              &Vs[cur ^ 1][ss * 8]);
      }
    }

    // swapped QK^T: sc[rt][ct] C-layout = [row=k-pos][col=q-row]
    f32x4 sc[2][4];
#pragma unroll
    for (int rt = 0; rt < 2; ++rt)
#pragma unroll
      for (int ct = 0; ct < 4; ++ct) sc[rt][ct] = (f32x4){0.f, 0.f, 0.f, 0.f};
    __builtin_amdgcn_s_setprio(1);
#pragma unroll
    for (int ct = 0; ct < 4; ++ct) {
      const unsigned short* kbase = &Ks[cur][(ct * 16 + l15) * 128];
#pragma unroll
      for (int kb = 0; kb < 2; ++kb) {
        bf16x8 kh = *(const bf16x8*)(kbase + ((kb * 8 + quad) ^ l15) * 8);
        bf16x8 kl = *(const bf16x8*)(kbase + ((kb * 8 + quad + 4) ^ l15) * 8);
#pragma unroll
        for (int rt = 0; rt < 2; ++rt) {
          sc[rt][ct] = __builtin_amdgcn_mfma_f32_16x16x32_bf16(kh, qf[rt][kb][0], sc[rt][ct], 0, 0, 0);
          sc[rt][ct] = __builtin_amdgcn_mfma_f32_16x16x32_bf16(kl, qf[rt][kb][0], sc[rt][ct], 0, 0, 0);
          sc[rt][ct] = __builtin_amdgcn_mfma_f32_16x16x32_bf16(kh, qf[rt][kb][1], sc[rt][ct], 0, 0, 0);
        }
      }
    }
    __builtin_amdgcn_s_setprio(0);

    // softmax + packed P-write: lane owns q-row l15, k = ct*16 + quad*4 + r
#pragma unroll
    for (int rt = 0; rt < 2; ++rt) {
      const int prow = w * 32 + rt * 16 + l15;
      const int pk = (l15 >> 1) & 7;
      unsigned short* prowp = &Ps[prow * 64 + (quad & 1) * 4];
#pragma unroll
      for (int ct = 0; ct < 4; ++ct) {
        float e0 = __expf(sc[rt][ct][0] * 0.125f);
        float e1 = __expf(sc[rt][ct][1] * 0.125f);
        float e2 = __expf(sc[rt][ct][2] * 0.125f);
        float e3 = __expf(sc[rt][ct][3] * 0.125f);
        lpart[rt] += (e0 + e1) + (e2 + e3);
        unsigned plo, phi;
        asm("v_cvt_pk_bf16_f32 %0, %1, %2" : "=v"(plo) : "v"(e0), "v"(e1));
        asm("v_cvt_pk_bf16_f32 %0, %1, %2" : "=v"(phi) : "v"(e2), "v"(e3));
        uint2 pu;
        pu.x = plo;
        pu.y = phi;
        *(uint2*)(prowp + (((ct * 2 + (quad >> 1)) ^ pk)) * 8) = pu;
      }
    }
    // P is wave-private: same-wave DS order + lgkmcnt fence suffices.
    asm volatile("s_waitcnt lgkmcnt(0)" ::: "memory");
    __builtin_amdgcn_sched_barrier(0);

    int rk = (l15 >> 1) & 7;
#pragma unroll
    for (int kb = 0; kb < 2; ++kb) {
      bf16x8 pf[2];
#pragma unroll
      for (int rt = 0; rt < 2; ++rt)
        pf[rt] = *(const bf16x8*)(&Ps[(w * 32 + rt * 16 + l15) * 64 +
                                      (((kb * 4 + quad) ^ rk)) * 8]);
      __builtin_amdgcn_s_setprio(1);
#pragma unroll
      for (int nt = 0; nt < 4; ++nt) {
        const unsigned short* vb = &Vs[cur][(nt * 16 + l15) * 128];
        bf16x8 vh = *(const bf16x8*)(vb + (((kb * 4 + quad) ^ l15)) * 8);
        bf16x8 vl = *(const bf16x8*)(vb + (((kb * 4 + quad + 8) ^ l15)) * 8);
#pragma unroll
        for (int rt = 0; rt < 2; ++rt) {
          o[rt][nt] = __builtin_amdgcn_mfma_f32_16x16x32_bf16(pf[rt], vh, o[rt][nt], 0, 0, 0);
          o[rt][nt] = __builtin_amdgcn_mfma_f32_16x16x32_bf16(pf[rt], vl, o[rt][nt], 0, 0, 0);
        }
      }
      __builtin_amdgcn_s_setprio(0);
    }
    // pf reads complete before next iteration's P writes (same-wave order).
    cur ^= 1;
  }

#pragma unroll
  for (int rt = 0; rt < 2; ++rt) {
    float lv = lpart[rt];
    lv += __shfl_xor(lv, 16, 64);
    lv += __shfl_xor(lv, 32, 64);
    float invv = 1.f / lv;  // q-row l15, replicated across quads
    float inv[4];
#pragma unroll
    for (int r = 0; r < 4; ++r) inv[r] = __shfl(invv, quad * 4 + r, 64);
#pragma unroll
    for (int nt = 0; nt < 4; ++nt) {
      int c = h * 64 + nt * 16 + l15;
      int Bb = c >> 5;
      int d32 = c & 31;
      int ch = d32 >> 3, off = d32 & 7;
#pragma unroll
      for (int r = 0; r < 4; ++r) {
        float val = o[rt][nt][r] * inv[r];
        int srow = qt * 128 + w * 32 + rt * 16 + quad * 4 + r;
        int key = srow & 7;
        size_t g = (size_t)(b * SLEN + srow) * 2048 + Bb * 64;
        unsigned short hv, lv2;
        splitbf(val, hv, lv2);
        a_all[g + ((ch ^ key)) * 8 + off] = hv;
        a_all[g + (((ch + 4) ^ key)) * 8 + off] = lv2;
      }
    }
  }
}

extern "C" void kernel_launch(void* const* d_in, const int* in_sizes, int n_in,
                              void* d_out, int out_size, void* d_ws,
                              size_t ws_size, hipStream_t stream) {
  (void)in_sizes; (void)n_in; (void)out_size; (void)ws_size;
  const float* Q = (const float*)d_in[0];
  const float* K = (const float*)d_in[1];
  const float* V = (const float*)d_in[2];
  const float* Wq = (const float*)d_in[3];
  const float* bq = (const float*)d_in[4];
  const float* Wk = (const float*)d_in[5];
  const float* bk = (const float*)d_in[6];
  const float* Wv = (const float*)d_in[7];
  const float* bv = (const float*)d_in[8];
  const float* Wo = (const float*)d_in[9];
  const float* bo = (const float*)d_in[10];
  float* out = (float*)d_out;

  // ws layout (u16 units), 112 MB total:
  //   q_all [0,8M)  k_all [8M,16M)  vt [16M,24M)
  //   a_all [24M,32M) -- Wqt/Wkt/Wvt overlaid (dead before attn writes a_all)
  //   Xp    [32M,56M) -- 3x 8M u16 packed split inputs (dead after proj)
  //   Wot overlays q_all (dead after attn)
  unsigned short* us = (unsigned short*)d_ws;
  const size_t M8 = 8u * 1024 * 1024;
  unsigned short* q_all = us;
  unsigned short* k_all = us + M8;
  unsigned short* vt = us + 2 * M8;
  unsigned short* a_all = us + 3 * M8;
  unsigned short* Wqt = a_all;
  unsigned short* Wkt = a_all + 2 * 1024 * 1024;
  unsigned short* Wvt = a_all + 4 * 1024 * 1024;
  unsigned short* Xp = us + 4 * M8;
  unsigned short* Wot = q_all;

  convert_w<<<dim3(16, 16, 3), 256, 0, stream>>>(Wq, Wk, Wv, Wqt, Wkt, Wvt);
  convert_x<<<dim3(4096, 3), 256, 0, stream>>>(Q, K, V, Xp);
  proj_gemm<<<dim3(4, 16, 3), 512, 0, stream>>>(Xp, Wqt, Wkt, Wvt, bq, bk, bv,
                                                q_all, k_all, vt);
  attn_kernel<<<dim3(SLEN / 128, NH, BATCH), 256, 0, stream>>>(q_all, k_all,
                                                               vt, a_all);
  convert_wo<<<dim3(1024), 256, 0, stream>>>(Wo, Wot);
  out_gemm<<<dim3(16, 16), 512, 0, stream>>>(a_all, Wot, bo, out);
}

// Round 11
// 331.152 us; speedup vs baseline: 1.0129x; 1.0129x over previous
//
#include <hip/hip_runtime.h>
#include <math.h>

#define BATCH 2
#define SLEN 2048
#define DM 1024
#define NH 16
#define DK 64
#define STILES (SLEN / 64)  // 32

typedef __attribute__((ext_vector_type(8))) __bf16 bf16x8;
typedef __attribute__((ext_vector_type(4))) float f32x4;

__device__ __forceinline__ unsigned short f2bf(float x) {  // round-nearest
  unsigned u = __builtin_bit_cast(unsigned, x);
  unsigned r = (u + 0x7fffu + ((u >> 16) & 1u)) >> 16;
  return (unsigned short)r;
}
// cheap truncation split: x ~= hi + lo to ~2^-16 relative
__device__ __forceinline__ void splitbf(float x, unsigned short& h,
                                        unsigned short& l) {
  unsigned u = __builtin_bit_cast(unsigned, x);
  h = (unsigned short)(u >> 16);
  float hf = __builtin_bit_cast(float, u & 0xffff0000u);
  l = (unsigned short)(__builtin_bit_cast(unsigned, x - hf) >> 16);
}

// async global->LDS, 16 B per lane
__device__ __forceinline__ void gld16(const unsigned short* g,
                                      unsigned short* l) {
  __builtin_amdgcn_global_load_lds(
      (const __attribute__((address_space(1))) void*)g,
      (__attribute__((address_space(3))) void*)l, 16, 0, 0);
}

// ---------------------------------------------------------------------------
// Weight transpose+split -> Wt[n][packed k], 64-u16 k-blocks [hi32|lo32],
// 16-B chunks XOR-swizzled with key (n&7).
// ---------------------------------------------------------------------------
__global__ __launch_bounds__(256)
void convert_w(const float* __restrict__ Wq, const float* __restrict__ Wk,
               const float* __restrict__ Wv, unsigned short* __restrict__ Wqt,
               unsigned short* __restrict__ Wkt,
               unsigned short* __restrict__ Wvt) {
  const int kb = blockIdx.x, h = blockIdx.y, z = blockIdx.z;
  const float* W = (z == 0 ? Wq : z == 1 ? Wk : Wv) +
                   ((size_t)h * DM + kb * 64) * DK;
  unsigned short* D = (z == 0 ? Wqt : z == 1 ? Wkt : Wvt);

  __shared__ float T[64][65];
  const int tid = threadIdx.x;
  {
    int r = tid >> 2, c0 = (tid & 3) * 16;
#pragma unroll
    for (int i = 0; i < 4; ++i) {
      float4 f = *(const float4*)(W + (size_t)r * DK + c0 + i * 4);
      T[r][c0 + i * 4 + 0] = f.x;
      T[r][c0 + i * 4 + 1] = f.y;
      T[r][c0 + i * 4 + 2] = f.z;
      T[r][c0 + i * 4 + 3] = f.w;
    }
  }
  __syncthreads();
  int j = tid >> 2, p = tid & 3;
  int n = h * 64 + j;
  int kloc = p * 16;
  unsigned short hi[16], lo[16];
#pragma unroll
  for (int i = 0; i < 16; ++i) splitbf(T[kloc + i][j], hi[i], lo[i]);
  int kglob = kb * 64 + kloc;
  int blk = kglob >> 5;
  int c0 = (kglob & 31) >> 3;
  int key = n & 7;
  unsigned short* rowp = D + (size_t)n * 2048 + blk * 64;
  uint4 u0, u1;
  u0.x = (unsigned)hi[0] | ((unsigned)hi[1] << 16);
  u0.y = (unsigned)hi[2] | ((unsigned)hi[3] << 16);
  u0.z = (unsigned)hi[4] | ((unsigned)hi[5] << 16);
  u0.w = (unsigned)hi[6] | ((unsigned)hi[7] << 16);
  u1.x = (unsigned)hi[8] | ((unsigned)hi[9] << 16);
  u1.y = (unsigned)hi[10] | ((unsigned)hi[11] << 16);
  u1.z = (unsigned)hi[12] | ((unsigned)hi[13] << 16);
  u1.w = (unsigned)hi[14] | ((unsigned)hi[15] << 16);
  *(uint4*)(rowp + ((c0 ^ key)) * 8) = u0;
  *(uint4*)(rowp + (((c0 + 1) ^ key)) * 8) = u1;
  u0.x = (unsigned)lo[0] | ((unsigned)lo[1] << 16);
  u0.y = (unsigned)lo[2] | ((unsigned)lo[3] << 16);
  u0.z = (unsigned)lo[4] | ((unsigned)lo[5] << 16);
  u0.w = (unsigned)lo[6] | ((unsigned)lo[7] << 16);
  u1.x = (unsigned)lo[8] | ((unsigned)lo[9] << 16);
  u1.y = (unsigned)lo[10] | ((unsigned)lo[11] << 16);
  u1.z = (unsigned)lo[12] | ((unsigned)lo[13] << 16);
  u1.w = (unsigned)lo[14] | ((unsigned)lo[15] << 16);
  *(uint4*)(rowp + (((c0 + 4) ^ key)) * 8) = u0;
  *(uint4*)(rowp + (((c0 + 5) ^ key)) * 8) = u1;
}

// ---------------------------------------------------------------------------
// X pre-split: X[m][k] fp32 -> Xp[z][m][packed k] (swizzle key m&7).
// grid (4096, 3), block 256.
// ---------------------------------------------------------------------------
__global__ __launch_bounds__(256)
void convert_x(const float* __restrict__ Q, const float* __restrict__ K,
               const float* __restrict__ V, unsigned short* __restrict__ Xp) {
  const int m = blockIdx.x, z = blockIdx.y;
  const float* src = (z == 0 ? Q : z == 1 ? K : V) + (size_t)m * DM;
  unsigned short* dst =
      Xp + (size_t)z * (8u * 1024 * 1024) + (size_t)m * 2048;
  const int k0 = threadIdx.x * 4;
  float4 f = *(const float4*)(src + k0);
  ushort4 h4, l4;
  splitbf(f.x, h4.x, l4.x);
  splitbf(f.y, h4.y, l4.y);
  splitbf(f.z, h4.z, l4.z);
  splitbf(f.w, h4.w, l4.w);
  int blk = k0 >> 5, ch = (k0 & 31) >> 3, off = k0 & 7, key = m & 7;
  unsigned short* rowp = dst + blk * 64;
  *(ushort4*)(rowp + ((ch ^ key)) * 8 + off) = h4;
  *(ushort4*)(rowp + (((ch + 4) ^ key)) * 8 + off) = l4;
}

// ---------------------------------------------------------------------------
// Wo pre-split: Wo[n][k] fp32 -> Wot[n][packed k] (swizzled like Wt).
// Runs AFTER attn (q_all region dead). grid 1024, block 256.
// ---------------------------------------------------------------------------
__global__ __launch_bounds__(256)
void convert_wo(const float* __restrict__ Wo, unsigned short* __restrict__ Wot) {
  const int n = blockIdx.x;
  const int t = threadIdx.x;
  const int k0 = t * 4;
  float4 f = *(const float4*)(Wo + (size_t)n * DM + k0);
  ushort4 h4, l4;
  splitbf(f.x, h4.x, l4.x);
  splitbf(f.y, h4.y, l4.y);
  splitbf(f.z, h4.z, l4.z);
  splitbf(f.w, h4.w, l4.w);
  int blk = k0 >> 5, ch = (k0 & 31) >> 3, off = k0 & 7, key = n & 7;
  unsigned short* rowp = Wot + (size_t)n * 2048 + blk * 64;
  *(ushort4*)(rowp + ((ch ^ key)) * 8 + off) = h4;
  *(ushort4*)(rowp + (((ch + 4) ^ key)) * 8 + off) = l4;
}

// ---------------------------------------------------------------------------
// 256x256 proj GEMM, race-free 1-phase-per-K-step counted-vmcnt schedule
// (exact R6 known-good version, packed Xp input).
// ---------------------------------------------------------------------------
__global__ __launch_bounds__(512, 2)
void proj_gemm(const unsigned short* __restrict__ Xp,
               const unsigned short* __restrict__ Wqt,
               const unsigned short* __restrict__ Wkt,
               const unsigned short* __restrict__ Wvt,
               const float* __restrict__ bq, const float* __restrict__ bk,
               const float* __restrict__ bv, unsigned short* __restrict__ q_all,
               unsigned short* __restrict__ k_all,
               unsigned short* __restrict__ vt) {
  const int ntile = blockIdx.x, mt = blockIdx.y, z = blockIdx.z;
  const unsigned short* Bw = (z == 0 ? Wqt : z == 1 ? Wkt : Wvt);
  const float* bias = (z == 0 ? bq : z == 1 ? bk : bv);

  __shared__ alignas(16) unsigned short As[2][256 * 64];
  __shared__ alignas(16) unsigned short Bs[2][256 * 64];

  const int tid = threadIdx.x;
  const int lane = tid & 63, w = tid >> 6;
  const int l15 = lane & 15, quad = lane >> 4;
  const int wm = (w >> 2) * 128, wn = (w & 3) * 64;
  const int kx = l15 & 7;

  const unsigned short* Ap =
      Xp + (size_t)z * (8u * 1024 * 1024) + (size_t)(mt * 256) * 2048;
  const unsigned short* Bp = Bw + (size_t)(ntile * 256) * 2048;

  // full-tile linear stage: 4 A chunks + 4 B chunks per thread (8 gld16)
#define STAGE(bf, t)                                                          \
  do {                                                                        \
    _Pragma("unroll") for (int it_ = 0; it_ < 4; ++it_) {                     \
      int s_ = tid + it_ * 512;                                               \
      int r_ = s_ >> 3, sg_ = s_ & 7;                                         \
      gld16(Ap + (size_t)r_ * 2048 + (t)*64 + sg_ * 8, &As[bf][s_ * 8]);      \
    }                                                                         \
    _Pragma("unroll") for (int it_ = 0; it_ < 4; ++it_) {                     \
      int s_ = tid + it_ * 512;                                               \
      int r_ = s_ >> 3, sg_ = s_ & 7;                                         \
      gld16(Bp + (size_t)r_ * 2048 + (t)*64 + sg_ * 8, &Bs[bf][s_ * 8]);      \
    }                                                                         \
  } while (0)
#define VMW(n) asm volatile("s_waitcnt vmcnt(" #n ")" ::: "memory")

  f32x4 acc[2][2][4][2];
#pragma unroll
  for (int a0 = 0; a0 < 2; ++a0)
#pragma unroll
    for (int a1 = 0; a1 < 2; ++a1)
#pragma unroll
      for (int a2 = 0; a2 < 4; ++a2)
#pragma unroll
        for (int a3 = 0; a3 < 2; ++a3)
          acc[a0][a1][a2][a3] = (f32x4){0.f, 0.f, 0.f, 0.f};

  STAGE(0, 0);

#pragma unroll 1
  for (int t = 0; t < 32; ++t) {
    const int buf = t & 1;
    if (t + 1 < 32) {
      STAGE(buf ^ 1, t + 1);  // target sealed by previous end-barrier
      VMW(8);                 // own stage(t) landed; stage(t+1) in flight
    } else {
      VMW(0);
    }
    __builtin_amdgcn_s_barrier();  // all waves' stage(t) landed

    // B frags once per K-step (8 reads) + A-QM0 (8 reads)
    bf16x8 bh[2][2], bl[2][2];
#pragma unroll
    for (int qn = 0; qn < 2; ++qn)
#pragma unroll
      for (int j = 0; j < 2; ++j) {
        const unsigned short* p = &Bs[buf][(wn + qn * 32 + j * 16 + l15) * 64];
        bh[qn][j] = *(const bf16x8*)(p + ((quad ^ kx)) * 8);
        bl[qn][j] = *(const bf16x8*)(p + (((quad + 4) ^ kx)) * 8);
      }
    bf16x8 ah[4], al[4];
#pragma unroll
    for (int i = 0; i < 4; ++i) {
      const unsigned short* p = &As[buf][(wm + i * 16 + l15) * 64];
      ah[i] = *(const bf16x8*)(p + ((quad ^ kx)) * 8);
      al[i] = *(const bf16x8*)(p + (((quad + 4) ^ kx)) * 8);
    }
    // A-QM1 (8 reads) issued now; lgkm(8) below lets them land under QM0 MFMA
    bf16x8 ah1[4], al1[4];
#pragma unroll
    for (int i = 0; i < 4; ++i) {
      const unsigned short* p = &As[buf][(wm + 64 + i * 16 + l15) * 64];
      ah1[i] = *(const bf16x8*)(p + ((quad ^ kx)) * 8);
      al1[i] = *(const bf16x8*)(p + (((quad + 4) ^ kx)) * 8);
    }
    asm volatile("s_waitcnt lgkmcnt(8)" ::: "memory");  // B+A0 done
    __builtin_amdgcn_sched_barrier(0);
    __builtin_amdgcn_s_setprio(1);
#pragma unroll
    for (int qn = 0; qn < 2; ++qn)
#pragma unroll
      for (int j = 0; j < 2; ++j)
#pragma unroll
        for (int i = 0; i < 4; ++i) {
          acc[0][qn][i][j] = __builtin_amdgcn_mfma_f32_16x16x32_bf16(
              ah[i], bh[qn][j], acc[0][qn][i][j], 0, 0, 0);
          acc[0][qn][i][j] = __builtin_amdgcn_mfma_f32_16x16x32_bf16(
              al[i], bh[qn][j], acc[0][qn][i][j], 0, 0, 0);
          acc[0][qn][i][j] = __builtin_amdgcn_mfma_f32_16x16x32_bf16(
              ah[i], bl[qn][j], acc[0][qn][i][j], 0, 0, 0);
        }
    __builtin_amdgcn_s_setprio(0);
    asm volatile("s_waitcnt lgkmcnt(0)" ::: "memory");  // A1 done
    __builtin_amdgcn_sched_barrier(0);
    __builtin_amdgcn_s_setprio(1);
#pragma unroll
    for (int qn = 0; qn < 2; ++qn)
#pragma unroll
      for (int j = 0; j < 2; ++j)
#pragma unroll
        for (int i = 0; i < 4; ++i) {
          acc[1][qn][i][j] = __builtin_amdgcn_mfma_f32_16x16x32_bf16(
              ah1[i], bh[qn][j], acc[1][qn][i][j], 0, 0, 0);
          acc[1][qn][i][j] = __builtin_amdgcn_mfma_f32_16x16x32_bf16(
              al1[i], bh[qn][j], acc[1][qn][i][j], 0, 0, 0);
          acc[1][qn][i][j] = __builtin_amdgcn_mfma_f32_16x16x32_bf16(
              ah1[i], bl[qn][j], acc[1][qn][i][j], 0, 0, 0);
        }
    __builtin_amdgcn_s_setprio(0);
    __builtin_amdgcn_sched_barrier(0);
    __builtin_amdgcn_s_barrier();  // seal this phase's reads
  }
#undef VMW
#undef STAGE

  if (z <= 1) {
    unsigned short* dst = (z == 0 ? q_all : k_all);
#pragma unroll
    for (int qm = 0; qm < 2; ++qm)
#pragma unroll
      for (int qn = 0; qn < 2; ++qn)
#pragma unroll
        for (int i = 0; i < 4; ++i)
#pragma unroll
          for (int j = 0; j < 2; ++j) {
            int n = ntile * 256 + wn + qn * 32 + j * 16 + l15;
            int hh_ = n >> 6, d = n & 63;
            int chi = (d >> 5) * 8 + ((d & 31) >> 3);
            float bn = bias[n];
#pragma unroll
            for (int r = 0; r < 4; ++r) {
              int m = mt * 256 + wm + qm * 64 + i * 16 + quad * 4 + r;
              int key = m & 15;
              size_t rb = (size_t)m * 2048 + hh_ * 128;
              unsigned short hv, lv;
              splitbf(acc[qm][qn][i][j][r] + bn, hv, lv);
              dst[rb + ((chi ^ key)) * 8 + (d & 7)] = hv;
              dst[rb + (((chi + 4) ^ key)) * 8 + (d & 7)] = lv;
            }
          }
  } else {
#pragma unroll
    for (int qm = 0; qm < 2; ++qm)
#pragma unroll
      for (int qn = 0; qn < 2; ++qn)
#pragma unroll
        for (int i = 0; i < 4; ++i)
#pragma unroll
          for (int j = 0; j < 2; ++j) {
            int n = ntile * 256 + wn + qn * 32 + j * 16 + l15;
            int h = n >> 6, d = n & 63;
            float bn = bias[n];
            int m0 = mt * 256 + wm + qm * 64 + i * 16 + quad * 4;
            int b = m0 >> 11, s0_ = m0 & 2047;
            int kt = s0_ >> 6, sl = s0_ & 63;
            int ch = sl >> 3, off = sl & 7, key = d & 15;
            ushort4 h4, l4;
            splitbf(acc[qm][qn][i][j][0] + bn, h4.x, l4.x);
            splitbf(acc[qm][qn][i][j][1] + bn, h4.y, l4.y);
            splitbf(acc[qm][qn][i][j][2] + bn, h4.z, l4.z);
            splitbf(acc[qm][qn][i][j][3] + bn, h4.w, l4.w);
            size_t base =
                (size_t)(b * NH + h) * 262144 + (size_t)d * 4096 + kt * 128;
            *(ushort4*)(vt + base + ((ch ^ key)) * 8 + off) = h4;
            *(ushort4*)(vt + base + (((ch + 8) ^ key)) * 8 + off) = l4;
          }
  }
}

// ---------------------------------------------------------------------------
// Output GEMM, race-free counted-vmcnt template at 256x64 tile (exact R6
// known-good version).
// ---------------------------------------------------------------------------
__global__ __launch_bounds__(512, 2)
void out_gemm(const unsigned short* __restrict__ a_all,
              const unsigned short* __restrict__ Wot,
              const float* __restrict__ bo, float* __restrict__ out) {
  const int ntile = blockIdx.x, mt = blockIdx.y;

  __shared__ alignas(16) unsigned short As[2][256 * 64];  // 64 KB
  __shared__ alignas(16) unsigned short Bs[2][64 * 64];   // 16 KB

  const int tid = threadIdx.x;
  const int lane = tid & 63, w = tid >> 6;
  const int l15 = lane & 15, quad = lane >> 4;
  const int wm = (w >> 1) * 64, wn = (w & 1) * 32;
  const int kx = l15 & 7;

  const unsigned short* Ap = a_all + (size_t)(mt * 256) * 2048;
  const unsigned short* Bp = Wot + (size_t)(ntile * 64) * 2048;

#define STAGEO(bf, t)                                                         \
  do {                                                                        \
    _Pragma("unroll") for (int it_ = 0; it_ < 4; ++it_) {                     \
      int s_ = tid + it_ * 512;                                               \
      int r_ = s_ >> 3, sg_ = s_ & 7;                                         \
      gld16(Ap + (size_t)r_ * 2048 + (t)*64 + sg_ * 8, &As[bf][s_ * 8]);      \
    }                                                                         \
    {                                                                         \
      int s_ = tid;                                                           \
      int r_ = s_ >> 3, sg_ = s_ & 7;                                         \
      gld16(Bp + (size_t)r_ * 2048 + (t)*64 + sg_ * 8, &Bs[bf][s_ * 8]);      \
    }                                                                         \
  } while (0)
#define VMW(n) asm volatile("s_waitcnt vmcnt(" #n ")" ::: "memory")

  f32x4 acc[4][2];
#pragma unroll
  for (int i = 0; i < 4; ++i)
#pragma unroll
    for (int j = 0; j < 2; ++j) acc[i][j] = (f32x4){0.f, 0.f, 0.f, 0.f};

  STAGEO(0, 0);

#pragma unroll 1
  for (int t = 0; t < 32; ++t) {
    const int buf = t & 1;
    if (t + 1 < 32) {
      STAGEO(buf ^ 1, t + 1);
      VMW(5);
    } else {
      VMW(0);
    }
    __builtin_amdgcn_s_barrier();

    bf16x8 bh[2], bl[2];
#pragma unroll
    for (int j = 0; j < 2; ++j) {
      const unsigned short* p = &Bs[buf][(wn + j * 16 + l15) * 64];
      bh[j] = *(const bf16x8*)(p + ((quad ^ kx)) * 8);
      bl[j] = *(const bf16x8*)(p + (((quad + 4) ^ kx)) * 8);
    }
    bf16x8 ah[4], al[4];
#pragma unroll
    for (int i = 0; i < 4; ++i) {
      const unsigned short* p = &As[buf][(wm + i * 16 + l15) * 64];
      ah[i] = *(const bf16x8*)(p + ((quad ^ kx)) * 8);
      al[i] = *(const bf16x8*)(p + (((quad + 4) ^ kx)) * 8);
    }
    asm volatile("s_waitcnt lgkmcnt(0)" ::: "memory");
    __builtin_amdgcn_sched_barrier(0);
    __builtin_amdgcn_s_setprio(1);
#pragma unroll
    for (int j = 0; j < 2; ++j)
#pragma unroll
      for (int i = 0; i < 4; ++i) {
        acc[i][j] = __builtin_amdgcn_mfma_f32_16x16x32_bf16(ah[i], bh[j], acc[i][j], 0, 0, 0);
        acc[i][j] = __builtin_amdgcn_mfma_f32_16x16x32_bf16(al[i], bh[j], acc[i][j], 0, 0, 0);
        acc[i][j] = __builtin_amdgcn_mfma_f32_16x16x32_bf16(ah[i], bl[j], acc[i][j], 0, 0, 0);
      }
    __builtin_amdgcn_s_setprio(0);
    __builtin_amdgcn_sched_barrier(0);
    __builtin_amdgcn_s_barrier();
  }
#undef VMW
#undef STAGEO

#pragma unroll
  for (int i = 0; i < 4; ++i)
#pragma unroll
    for (int j = 0; j < 2; ++j) {
      int n = ntile * 64 + wn + j * 16 + l15;
      float bn = bo[n];
#pragma unroll
      for (int r = 0; r < 4; ++r) {
        int m = mt * 256 + wm + i * 16 + quad * 4 + r;
        out[(size_t)m * DM + n] = acc[i][j][r] + bn;
      }
    }
}

// ---------------------------------------------------------------------------
// MFMA flash attention (exact R6 math) + XCD-aware block remap (T1): all 16
// q-tile blocks of one head share bid&7, so the head's K/V/vt (~1.5 MB) stays
// in ONE XCD's L2 (4 heads/XCD = ~4 MB = L2 size; 512 blocks co-resident at
// 2/CU). Remap is bijective: bid = 8*((g>>3)*16 + qt) + (g&7), g = b*16+h.
// Zero arithmetic change.
// ---------------------------------------------------------------------------
__global__ __launch_bounds__(256)
void attn_kernel(const unsigned short* __restrict__ q_all,
                 const unsigned short* __restrict__ k_all,
                 const unsigned short* __restrict__ vt,
                 unsigned short* __restrict__ a_all) {
  const int bid = blockIdx.x + (blockIdx.y << 4) + (blockIdx.z << 8);
  const int xcd = bid & 7, slot = bid >> 3;
  const int g = ((slot >> 4) << 3) + xcd;  // global head id in [0,32)
  const int qt = slot & 15, h = g & 15, b = g >> 4;
  const unsigned short* vp = vt + (size_t)(b * NH + h) * 262144;

  __shared__ alignas(16) unsigned short Ks[2][64 * 128];
  __shared__ alignas(16) unsigned short Vs[2][64 * 128];
  __shared__ alignas(16) unsigned short Ps[128 * 64];

  const int tid = threadIdx.x;
  const int lane = tid & 63;
  const int w = tid >> 6;
  const int l15 = lane & 15;
  const int quad = lane >> 4;

  bf16x8 qf[2][2][2];
#pragma unroll
  for (int rt = 0; rt < 2; ++rt) {
    const unsigned short* qrow =
        q_all + (size_t)(b * SLEN + qt * 128 + w * 32 + rt * 16 + l15) * 2048 +
        h * 128;
#pragma unroll
    for (int kb = 0; kb < 2; ++kb) {
      qf[rt][kb][0] = *(const bf16x8*)(qrow + ((kb * 8 + quad) ^ l15) * 8);
      qf[rt][kb][1] = *(const bf16x8*)(qrow + ((kb * 8 + quad + 4) ^ l15) * 8);
    }
  }

  // prologue: stage kt=0
  {
    const unsigned short* ksrc = k_all + (size_t)(b * SLEN) * 2048 + h * 128;
#pragma unroll
    for (int it = 0; it < 4; ++it) {
      int ss = it * 256 + tid;
      int r = ss >> 4, p = ss & 15;
      gld16(ksrc + (size_t)r * 2048 + p * 8, &Ks[0][ss * 8]);
    }
#pragma unroll
    for (int it = 0; it < 4; ++it) {
      int ss = it * 256 + tid;
      int d = ss >> 4, p = ss & 15;
      gld16(vp + (size_t)d * 4096 + p * 8, &Vs[0][ss * 8]);
    }
  }

  f32x4 o[2][4];
  float lpart[2];
#pragma unroll
  for (int rt = 0; rt < 2; ++rt) {
    lpart[rt] = 0.f;
#pragma unroll
    for (int nt = 0; nt < 4; ++nt) o[rt][nt] = (f32x4){0.f, 0.f, 0.f, 0.f};
  }

  int cur = 0;
  for (int kt = 0; kt < STILES; ++kt) {
    __syncthreads();  // glds(kt) done (aged through prev iteration for kt>0)

    if (kt + 1 < STILES) {  // prefetch kt+1 into alt buffers
      const unsigned short* ksrc =
          k_all + (size_t)(b * SLEN + (kt + 1) * 64) * 2048 + h * 128;
#pragma unroll
      for (int it = 0; it < 4; ++it) {
        int ss = it * 256 + tid;
        int r = ss >> 4, p = ss & 15;
        gld16(ksrc + (size_t)r * 2048 + p * 8, &Ks[cur ^ 1][ss * 8]);
      }
#pragma unroll
      for (int it = 0; it < 4; ++it) {
        int ss = it * 256 + tid;
        int d = ss >> 4, p = ss & 15;
        gld16(vp + (size_t)d * 4096 + (kt + 1) * 128 + p * 8,
              &Vs[cur ^ 1][ss * 8]);
      }
    }

    // swapped QK^T: sc[rt][ct] C-layout = [row=k-pos][col=q-row]
    f32x4 sc[2][4];
#pragma unroll
    for (int rt = 0; rt < 2; ++rt)
#pragma unroll
      for (int ct = 0; ct < 4; ++ct) sc[rt][ct] = (f32x4){0.f, 0.f, 0.f, 0.f};
    __builtin_amdgcn_s_setprio(1);
#pragma unroll
    for (int ct = 0; ct < 4; ++ct) {
      const unsigned short* kbase = &Ks[cur][(ct * 16 + l15) * 128];
#pragma unroll
      for (int kb = 0; kb < 2; ++kb) {
        bf16x8 kh = *(const bf16x8*)(kbase + ((kb * 8 + quad) ^ l15) * 8);
        bf16x8 kl = *(const bf16x8*)(kbase + ((kb * 8 + quad + 4) ^ l15) * 8);
#pragma unroll
        for (int rt = 0; rt < 2; ++rt) {
          sc[rt][ct] = __builtin_amdgcn_mfma_f32_16x16x32_bf16(kh, qf[rt][kb][0], sc[rt][ct], 0, 0, 0);
          sc[rt][ct] = __builtin_amdgcn_mfma_f32_16x16x32_bf16(kl, qf[rt][kb][0], sc[rt][ct], 0, 0, 0);
          sc[rt][ct] = __builtin_amdgcn_mfma_f32_16x16x32_bf16(kh, qf[rt][kb][1], sc[rt][ct], 0, 0, 0);
        }
      }
    }
    __builtin_amdgcn_s_setprio(0);

    // softmax + packed P-write: lane owns q-row l15, k = ct*16 + quad*4 + r
#pragma unroll
    for (int rt = 0; rt < 2; ++rt) {
      const int prow = w * 32 + rt * 16 + l15;
      const int pk = (l15 >> 1) & 7;
      unsigned short* prowp = &Ps[prow * 64 + (quad & 1) * 4];
#pragma unroll
      for (int ct = 0; ct < 4; ++ct) {
        float e0 = __expf(sc[rt][ct][0] * 0.125f);
        float e1 = __expf(sc[rt][ct][1] * 0.125f);
        float e2 = __expf(sc[rt][ct][2] * 0.125f);
        float e3 = __expf(sc[rt][ct][3] * 0.125f);
        lpart[rt] += (e0 + e1) + (e2 + e3);
        unsigned plo, phi;
        asm("v_cvt_pk_bf16_f32 %0, %1, %2" : "=v"(plo) : "v"(e0), "v"(e1));
        asm("v_cvt_pk_bf16_f32 %0, %1, %2" : "=v"(phi) : "v"(e2), "v"(e3));
        uint2 pu;
        pu.x = plo;
        pu.y = phi;
        *(uint2*)(prowp + (((ct * 2 + (quad >> 1)) ^ pk)) * 8) = pu;
      }
    }
    // P is wave-private: same-wave DS order + lgkmcnt fence suffices.
    asm volatile("s_waitcnt lgkmcnt(0)" ::: "memory");
    __builtin_amdgcn_sched_barrier(0);

    int rk = (l15 >> 1) & 7;
#pragma unroll
    for (int kb = 0; kb < 2; ++kb) {
      bf16x8 pf[2];
#pragma unroll
      for (int rt = 0; rt < 2; ++rt)
        pf[rt] = *(const bf16x8*)(&Ps[(w * 32 + rt * 16 + l15) * 64 +
                                      (((kb * 4 + quad) ^ rk)) * 8]);
      __builtin_amdgcn_s_setprio(1);
#pragma unroll
      for (int nt = 0; nt < 4; ++nt) {
        const unsigned short* vb = &Vs[cur][(nt * 16 + l15) * 128];
        bf16x8 vh = *(const bf16x8*)(vb + (((kb * 4 + quad) ^ l15)) * 8);
        bf16x8 vl = *(const bf16x8*)(vb + (((kb * 4 + quad + 8) ^ l15)) * 8);
#pragma unroll
        for (int rt = 0; rt < 2; ++rt) {
          o[rt][nt] = __builtin_amdgcn_mfma_f32_16x16x32_bf16(pf[rt], vh, o[rt][nt], 0, 0, 0);
          o[rt][nt] = __builtin_amdgcn_mfma_f32_16x16x32_bf16(pf[rt], vl, o[rt][nt], 0, 0, 0);
        }
      }
      __builtin_amdgcn_s_setprio(0);
    }
    // pf reads complete before next iteration's P writes (same-wave order).
    cur ^= 1;
  }

#pragma unroll
  for (int rt = 0; rt < 2; ++rt) {
    float lv = lpart[rt];
    lv += __shfl_xor(lv, 16, 64);
    lv += __shfl_xor(lv, 32, 64);
    float invv = 1.f / lv;  // q-row l15, replicated across quads
    float inv[4];
#pragma unroll
    for (int r = 0; r < 4; ++r) inv[r] = __shfl(invv, quad * 4 + r, 64);
#pragma unroll
    for (int nt = 0; nt < 4; ++nt) {
      int c = h * 64 + nt * 16 + l15;
      int Bb = c >> 5;
      int d32 = c & 31;
      int ch = d32 >> 3, off = d32 & 7;
#pragma unroll
      for (int r = 0; r < 4; ++r) {
        float val = o[rt][nt][r] * inv[r];
        int srow = qt * 128 + w * 32 + rt * 16 + quad * 4 + r;
        int key = srow & 7;
        size_t g2 = (size_t)(b * SLEN + srow) * 2048 + Bb * 64;
        unsigned short hv, lv2;
        splitbf(val, hv, lv2);
        a_all[g2 + ((ch ^ key)) * 8 + off] = hv;
        a_all[g2 + (((ch + 4) ^ key)) * 8 + off] = lv2;
      }
    }
  }
}

extern "C" void kernel_launch(void* const* d_in, const int* in_sizes, int n_in,
                              void* d_out, int out_size, void* d_ws,
                              size_t ws_size, hipStream_t stream) {
  (void)in_sizes; (void)n_in; (void)out_size; (void)ws_size;
  const float* Q = (const float*)d_in[0];
  const float* K = (const float*)d_in[1];
  const float* V = (const float*)d_in[2];
  const float* Wq = (const float*)d_in[3];
  const float* bq = (const float*)d_in[4];
  const float* Wk = (const float*)d_in[5];
  const float* bk = (const float*)d_in[6];
  const float* Wv = (const float*)d_in[7];
  const float* bv = (const float*)d_in[8];
  const float* Wo = (const float*)d_in[9];
  const float* bo = (const float*)d_in[10];
  float* out = (float*)d_out;

  // ws layout (u16 units), 112 MB total:
  //   q_all [0,8M)  k_all [8M,16M)  vt [16M,24M)
  //   a_all [24M,32M) -- Wqt/Wkt/Wvt overlaid (dead before attn writes a_all)
  //   Xp    [32M,56M) -- 3x 8M u16 packed split inputs (dead after proj)
  //   Wot overlays q_all (dead after attn)
  unsigned short* us = (unsigned short*)d_ws;
  const size_t M8 = 8u * 1024 * 1024;
  unsigned short* q_all = us;
  unsigned short* k_all = us + M8;
  unsigned short* vt = us + 2 * M8;
  unsigned short* a_all = us + 3 * M8;
  unsigned short* Wqt = a_all;
  unsigned short* Wkt = a_all + 2 * 1024 * 1024;
  unsigned short* Wvt = a_all + 4 * 1024 * 1024;
  unsigned short* Xp = us + 4 * M8;
  unsigned short* Wot = q_all;

  convert_w<<<dim3(16, 16, 3), 256, 0, stream>>>(Wq, Wk, Wv, Wqt, Wkt, Wvt);
  convert_x<<<dim3(4096, 3), 256, 0, stream>>>(Q, K, V, Xp);
  proj_gemm<<<dim3(4, 16, 3), 512, 0, stream>>>(Xp, Wqt, Wkt, Wvt, bq, bk, bv,
                                                q_all, k_all, vt);
  attn_kernel<<<dim3(SLEN / 128, NH, BATCH), 256, 0, stream>>>(q_all, k_all,
                                                               vt, a_all);
  convert_wo<<<dim3(1024), 256, 0, stream>>>(Wo, Wot);
  out_gemm<<<dim3(16, 16), 512, 0, stream>>>(a_all, Wot, bo, out);
}